// Round 11
// baseline (501.476 us; speedup 1.0000x reference)
//
#include <hip/hip_runtime.h>
#include <hip/hip_bf16.h>

typedef __hip_bfloat16 bf16;
typedef __attribute__((ext_vector_type(8))) short s16x8;   // 8 bf16 = 4 VGPRs
typedef __attribute__((ext_vector_type(4))) float f32x4;

#define MFMA16x16x32(A, B, C) __builtin_amdgcn_mfma_f32_16x16x32_bf16((A), (B), (C), 0, 0, 0)

__device__ __forceinline__ void async_copy16(const bf16* g, bf16* l) {
  __builtin_amdgcn_global_load_lds(
      (const __attribute__((address_space(1))) void*)g,
      (__attribute__((address_space(3))) void*)l, 16, 0, 0);
}

// XOR-swizzled LDS addressing for 128-B rows (64 bf16), 16-B chunks:
// chunk' = chunk ^ (row&7). Conflict-free (2-way max) for b128 patterns.
__device__ __forceinline__ int SW(int row, int chunk) {
  return row * 64 + (((chunk) ^ (row & 7)) << 3);
}

// ---------------------------------------------------------------------------
// merged cast: all 5 f32->bf16 casts in ONE dispatch (block-range routing).
// blocks: w_qkv 1728 | w_out 576 | w1 2304 | w2 2304 | src 6144  = 13056
// ---------------------------------------------------------------------------
__global__ __launch_bounds__(256)
void cast_all_kernel(const float* __restrict__ s0, bf16* __restrict__ d0,
                     const float* __restrict__ s1, bf16* __restrict__ d1,
                     const float* __restrict__ s2, bf16* __restrict__ d2,
                     const float* __restrict__ s3, bf16* __restrict__ d3,
                     const float* __restrict__ s4, bf16* __restrict__ d4) {
  int blk = blockIdx.x;
  const float* in; bf16* out;
  if (blk < 1728)      { in = s0; out = d0; }
  else if (blk < 2304) { in = s1; out = d1; blk -= 1728; }
  else if (blk < 4608) { in = s2; out = d2; blk -= 2304; }
  else if (blk < 6912) { in = s3; out = d3; blk -= 4608; }
  else                 { in = s4; out = d4; blk -= 6912; }
  const int i = (blk * 256 + threadIdx.x) * 4;
  const float4 f = *(const float4*)(in + i);
  out[i + 0] = (bf16)f.x; out[i + 1] = (bf16)f.y;
  out[i + 2] = (bf16)f.z; out[i + 3] = (bf16)f.w;
}

// ---------------------------------------------------------------------------
// GEMM: C = A[M,K]b @ B[N,K]^T b (+bias f32) (+ReLU) (+fp32 accumulate).
// 128xCN tile (CN = 128 or 64), BK=32, 256 threads, double-buffered LDS,
// one barrier per K-step. CN=64 narrow tile -> 3 blocks/CU for N=768.
// VT=0: plain store. VT=2: fused QKV routing (cols <1536 -> C, >=1536 ->
// per-head Vt scatter into C2); CN must be 128 for VT=2.
// ---------------------------------------------------------------------------
template <int RELU, int VT, int ACCUM, int CN, typename OutT>
__global__ __launch_bounds__(256)
void gemm_bt_kernel(const bf16* __restrict__ A, const bf16* __restrict__ B,
                    const float* __restrict__ bias, OutT* __restrict__ C,
                    int N, int K, int lda, int ldb, bf16* __restrict__ C2) {
  constexpr int NJ = CN / 32;              // col 16x16 tiles per wave (4 or 2)
  __shared__ __align__(16) bf16 As[2][128 * 32];
  __shared__ __align__(16) bf16 Bs[2][CN * 32];

  const int t = threadIdx.x;
  const int lane = t & 63;
  const int wave = t >> 6;
  const int wm = (wave >> 1) << 6;
  const int wn = (wave & 1) * (CN / 2);
  const int col16 = lane & 15;
  const int quad = lane >> 4;
  const int bm = blockIdx.x;
  const int bn = blockIdx.y;

  const bf16* Ag = A + (size_t)(bm * 128 + (t >> 2)) * lda + (t & 3) * 8;
  const bf16* Bg = B + (size_t)(bn * CN + (t >> 2)) * ldb + (t & 3) * 8;

  f32x4 acc[4][NJ] = {};

  // prologue: stage K-tile 0 into buffer 0
  async_copy16(Ag, &As[0][0] + t * 8);
  async_copy16(Ag + (size_t)64 * lda, &As[0][0] + 2048 + t * 8);
  async_copy16(Bg, &Bs[0][0] + t * 8);
  if (CN == 128)
    async_copy16(Bg + (size_t)64 * ldb, &Bs[0][0] + 2048 + t * 8);

  int n = 0;
  for (int k0 = 0; k0 < K; k0 += 32, n ^= 1) {
    __syncthreads();   // compiler drains vmcnt here -> buf n resident
    if (k0 + 32 < K) {
      const int k1 = k0 + 32;
      async_copy16(Ag + k1, &As[n ^ 1][0] + t * 8);
      async_copy16(Ag + (size_t)64 * lda + k1, &As[n ^ 1][0] + 2048 + t * 8);
      async_copy16(Bg + k1, &Bs[n ^ 1][0] + t * 8);
      if (CN == 128)
        async_copy16(Bg + (size_t)64 * ldb + k1, &Bs[n ^ 1][0] + 2048 + t * 8);
    }
    const bf16* asn = &As[n][0];
    const bf16* bsn = &Bs[n][0];

    s16x8 af[4], bfr[NJ];
#pragma unroll
    for (int i = 0; i < 4; i++)
      af[i] = *(const s16x8*)(asn + (wm + i * 16 + col16) * 32 + quad * 8);
#pragma unroll
    for (int j = 0; j < NJ; j++)
      bfr[j] = *(const s16x8*)(bsn + (wn + j * 16 + col16) * 32 + quad * 8);
#pragma unroll
    for (int i = 0; i < 4; i++)
#pragma unroll
      for (int j = 0; j < NJ; j++)
        acc[i][j] = MFMA16x16x32(af[i], bfr[j], acc[i][j]);
  }

  const int row0 = bm * 128 + wm + quad * 4;
  const int col0 = bn * CN + wn + col16;
#pragma unroll
  for (int j = 0; j < NJ; j++) {
    const int col = col0 + j * 16;
    const float bv = ACCUM ? 0.0f : bias[col];
#pragma unroll
    for (int i = 0; i < 4; i++) {
#pragma unroll
      for (int r = 0; r < 4; r++) {
        float v = acc[i][j][r] + bv;
        if (RELU) v = fmaxf(v, 0.0f);
        const int row = row0 + i * 16 + r;
        if (VT == 2) {
          if (col < 1536) {
            C[(size_t)row * N + col] = (OutT)v;
          } else {
            const int cc = col - 1536;
            C2[(size_t)((row >> 12) * 12 + (cc >> 6)) * 262144 +
               (cc & 63) * 4096 + (row & 4095)] = (bf16)v;
          }
        } else {
          const size_t idx = (size_t)row * N + col;
          if (ACCUM) v += ((const float*)C)[idx];
          C[idx] = (OutT)v;
        }
      }
    }
  }
}

// ---------------------------------------------------------------------------
// Flash attention, round-11: R8/R5 dataflow at KVBLK=32 and LDS = 32 KB
// EXACTLY (K dbuf 8 KB + V dbuf 8 KB + Ps 16 KB) -> 3 blocks/CU resident
// (the 768-block grid fits with zero tail; occupancy 8 -> 12 waves/CU).
// Per-64-keys DS traffic, MFMA count, and math are unchanged vs R8; only
// the barrier count doubles. S^T formulation, shift-free exp2 softmax,
// ones-MFMA l, 64 q/wave, K-SPLIT=2, XCD-group swizzle (FETCH 104->18.5 MB,
// R10-proven).
// Swizzles (bank-derived): Ks 128-B rows ^(row&7) [proven]; Vs 64-B rows
// chunk^(row&3) [uniform 8 acc/bank]; Ps [64q][32k] linear (b128 reads
// conflict-free; b64 writes 2-way, accepted).
// ---------------------------------------------------------------------------
__global__ __launch_bounds__(256, 3)
void attn_kernel(const bf16* __restrict__ QK, const bf16* __restrict__ Vt,
                 bf16* __restrict__ Opart, float* __restrict__ lbuf) {
  // pool (bf16): Ks[2] @0 (2048 ea) | Vs[2] @4096 | Ps[4] @8192 (2048 ea)
  __shared__ __align__(16) bf16 pool[16384];   // 32768 B

  const int t = threadIdx.x, lane = t & 63, wave = t >> 6;
  const int col16 = lane & 15, quad = lane >> 4;

  // XCD-group swizzle: w -> (work-x, head h, batch b); g%8 pins the KV
  // panel group to one XCD's L2.
  const int w = blockIdx.x + 32 * (blockIdx.y + 12 * blockIdx.z);
  const int g = (w & 7) + 8 * ((w >> 3) >> 5);
  const int x = (w >> 3) & 31;
  const int b = g / 12, h = g % 12;
  const int ks = x >> 4;                          // key-split index (0/1)
  const int qblk = x & 15;
  const int qw0 = qblk * 256 + wave * 64;

  // Q as B-frags (4 qtiles), pre-scaled by 0.125*log2(e)
  s16x8 bq[4][2];
#pragma unroll
  for (int qt = 0; qt < 4; qt++)
#pragma unroll
    for (int s = 0; s < 2; s++) {
      union { s16x8 v; bf16 hh[8]; } u;
      u.v = *(const s16x8*)(QK + (size_t)(b * 4096 + qw0 + qt * 16 + col16) * 1536 +
                            h * 64 + s * 32 + quad * 8);
#pragma unroll
      for (int e = 0; e < 8; e++) u.hh[e] = (bf16)((float)u.hh[e] * 0.18033688f);
      bq[qt][s] = u.v;
    }

  // all-ones A-fragment for the l-accumulating MFMA
  union { s16x8 v; short s_[8]; } uo1;
#pragma unroll
  for (int e = 0; e < 8; e++) uo1.s_[e] = (short)0x3F80;  // bf16 1.0
  const s16x8 aones = uo1.v;

  // staging addressing (pre-swizzled global source, linear LDS dest):
  // K tile [32 k][64 d], 128-B rows: t -> row t>>3, chunk (t&7)^(row&7)
  // V tile [64 d][32 k],  64-B rows: t -> row t>>2, chunk (t&3)^(row&3)
  const int krow = t >> 3;
  const int kch = (t & 7) ^ (krow & 7);
  const int vrow = t >> 2;
  const int vch = (t & 3) ^ (vrow & 3);
  const bf16* kgb = QK + (size_t)(b * 4096) * 1536 + 768 + h * 64;
  const bf16* vgb = Vt + (size_t)(b * 12 + h) * 262144;
  const bf16* ksrc = kgb + (size_t)krow * 1536 + kch * 8;
  const bf16* vsrc = vgb + (size_t)vrow * 4096 + vch * 8;

  f32x4 o[4][4] = {};            // O^T [dtile][qtile]
  f32x4 lacc[4] = {};            // l per qtile (all C-rows identical)
  bf16* pw = pool + 8192 + wave * 2048;   // per-wave P^T [64 q][32 k]

  const int kbeg = ks * 2048, kend = kbeg + 2048;

  // prologue: stage first 32-key tile into buffer 0 (1 K copy + 1 V copy)
  async_copy16(ksrc + (size_t)kbeg * 1536, pool + t * 8);
  async_copy16(vsrc + kbeg, pool + 4096 + t * 8);

  int n = 0;
  for (int k0 = kbeg; k0 < kend; k0 += 32, n ^= 1) {
    // barrier drains vmcnt -> tile k0 resident in buf n for all waves
    __syncthreads();
    if (k0 + 32 < kend) {
      async_copy16(ksrc + (size_t)(k0 + 32) * 1536, pool + (n ^ 1) * 2048 + t * 8);
      async_copy16(vsrc + (k0 + 32), pool + 4096 + (n ^ 1) * 2048 + t * 8);
    }
    const bf16* ksn = pool + n * 2048;          // [32 k][64 d] swz
    const bf16* vsn = pool + 4096 + n * 2048;   // [64 d][32 k] swz

    // K^T fragments (2 keytiles x 2 d-slices), read ONCE, used by 4 qtiles
    s16x8 ak[2][2];
#pragma unroll
    for (int s = 0; s < 2; s++)
#pragma unroll
      for (int kt = 0; kt < 2; kt++)
        ak[s][kt] = *(const s16x8*)(ksn + SW(kt * 16 + col16, s * 4 + quad));

    // per-keytile: S^T (log2 domain) -> shift-free softmax -> P^T to LDS
#pragma unroll
    for (int kt = 0; kt < 2; kt++) {
      f32x4 st[4] = {};
#pragma unroll
      for (int s = 0; s < 2; s++)
#pragma unroll
        for (int qt = 0; qt < 4; qt++)
          st[qt] = MFMA16x16x32(ak[s][kt], bq[qt][s], st[qt]);
#pragma unroll
      for (int qt = 0; qt < 4; qt++) {
        union { unsigned long long u; bf16 hh[4]; } pk;
#pragma unroll
        for (int r = 0; r < 4; r++)
          pk.hh[r] = (bf16)__builtin_amdgcn_exp2f(st[qt][r]);
        // P^T[q][k]: row q = qt*16+col16 (32-elem rows), keys kt*16+quad*4..+3
        *(unsigned long long*)(pw + (qt * 16 + col16) * 32 + kt * 16 + quad * 4) =
            pk.u;
      }
    }
    asm volatile("s_waitcnt lgkmcnt(0)" ::: "memory");

    // l += ones @ P^T (matrix pipe);  O^T += V^T @ P^T  (one K=32 slice)
    s16x8 bp[4];
#pragma unroll
    for (int qt = 0; qt < 4; qt++)
      bp[qt] = *(const s16x8*)(pw + (qt * 16 + col16) * 32 + quad * 8);
#pragma unroll
    for (int qt = 0; qt < 4; qt++)
      lacc[qt] = MFMA16x16x32(aones, bp[qt], lacc[qt]);
#pragma unroll
    for (int dt = 0; dt < 4; dt++) {
      const int vr = dt * 16 + col16;
      const s16x8 av = *(const s16x8*)(vsn + vr * 32 + ((quad ^ (vr & 3)) << 3));
#pragma unroll
      for (int qt = 0; qt < 4; qt++)
        o[dt][qt] = MFMA16x16x32(av, bp[qt], o[dt][qt]);
    }
  }

  // partial l: C/D col = lane&15 = q; every C-row holds the same value.
  if (lane < 16) {
#pragma unroll
    for (int qt = 0; qt < 4; qt++)
      lbuf[(size_t)ks * 98304 + (size_t)(b * 4096 + qw0 + qt * 16 + lane) * 12 + h] =
          lacc[qt][0];
  }

  // epilogue: repurpose the whole pool as per-wave [64 q][64 d] transpose
  // buffers (4 x 8 KB); barrier first — K/V/P regions are dead. (R9-proven.)
  __syncthreads();
  bf16* ep = pool + wave * 4096;
#pragma unroll
  for (int qt = 0; qt < 4; qt++)
#pragma unroll
    for (int dt = 0; dt < 4; dt++)
#pragma unroll
      for (int r = 0; r < 4; r++)
        ep[(qt * 16 + col16) * 64 + (((dt * 2 + (quad >> 1)) ^ (col16 & 7)) << 3) +
           (quad & 1) * 4 + r] = (bf16)(o[dt][qt][r]);
  asm volatile("s_waitcnt lgkmcnt(0)" ::: "memory");
  const int qrow = lane >> 1, chalf = (lane & 1) * 4;
#pragma unroll
  for (int h2 = 0; h2 < 2; h2++) {
    const int rl = h2 * 32 + qrow;
    bf16* dst = Opart + (size_t)ks * 6291456 +
                (size_t)(b * 4096 + qw0 + rl) * 768 + h * 64 + chalf * 8;
#pragma unroll
    for (int i = 0; i < 4; i++)
      *(s16x8*)(dst + i * 8) = *(const s16x8*)(ep + SW(rl, chalf + i));
  }
}

// ---------------------------------------------------------------------------
// combine: ctx = (O0 + O1) / (l0 + l1); 8 cols per thread, fully coalesced.
// ---------------------------------------------------------------------------
__global__ __launch_bounds__(256)
void attn_combine_kernel(const bf16* __restrict__ Opart,
                         const float* __restrict__ lbuf,
                         bf16* __restrict__ ctx) {
  const int i = blockIdx.x * 256 + threadIdx.x;   // [0, 8192*96)
  const int row = i / 96, c8 = i % 96;
  const int h = c8 >> 3;
  const float inv = 1.0f / (lbuf[(size_t)row * 12 + h] +
                            lbuf[98304 + (size_t)row * 12 + h]);
  union { s16x8 v; bf16 hh[8]; } ua, ub, uo;
  ua.v = *(const s16x8*)(Opart + (size_t)row * 768 + c8 * 8);
  ub.v = *(const s16x8*)(Opart + 6291456 + (size_t)row * 768 + c8 * 8);
#pragma unroll
  for (int j = 0; j < 8; j++)
    uo.hh[j] = (bf16)(((float)ua.hh[j] + (float)ub.hh[j]) * inv);
  *(s16x8*)(ctx + (size_t)row * 768 + c8 * 8) = uo.v;
}

// ---------------------------------------------------------------------------
// LN variants: ln_b: bf16 out of LN(f32 + f32); ln_f: f32 out of LN(bf16+f32)
// ---------------------------------------------------------------------------
__global__ __launch_bounds__(256)
void add_ln_b_kernel(const float* __restrict__ X, const float* __restrict__ Y,
                     const float* __restrict__ w, const float* __restrict__ b,
                     bf16* __restrict__ out) {
  const int row = blockIdx.x * 4 + (threadIdx.x >> 6);
  const int lane = threadIdx.x & 63;
  const float* x = X + (size_t)row * 768;
  const float* y = Y + (size_t)row * 768;
  float v[12];
  float s = 0.0f;
#pragma unroll
  for (int i = 0; i < 3; i++) {
    const int c = lane * 4 + i * 256;
    const float4 xf = *(const float4*)(x + c);
    const float4 yf = *(const float4*)(y + c);
    v[i * 4 + 0] = xf.x + yf.x; v[i * 4 + 1] = xf.y + yf.y;
    v[i * 4 + 2] = xf.z + yf.z; v[i * 4 + 3] = xf.w + yf.w;
    s += v[i * 4] + v[i * 4 + 1] + v[i * 4 + 2] + v[i * 4 + 3];
  }
#pragma unroll
  for (int off = 32; off > 0; off >>= 1) s += __shfl_xor(s, off, 64);
  const float mu = s * (1.0f / 768.0f);
  float var = 0.0f;
#pragma unroll
  for (int i = 0; i < 12; i++) { const float d = v[i] - mu; var += d * d; }
#pragma unroll
  for (int off = 32; off > 0; off >>= 1) var += __shfl_xor(var, off, 64);
  const float rs = rsqrtf(var * (1.0f / 768.0f) + 1e-5f);
#pragma unroll
  for (int i = 0; i < 12; i++) {
    const int c = lane * 4 + (i >> 2) * 256 + (i & 3);
    out[(size_t)row * 768 + c] = (bf16)((v[i] - mu) * rs * w[c] + b[c]);
  }
}

__global__ __launch_bounds__(256)
void add_ln_f_kernel(const bf16* __restrict__ X, const float* __restrict__ Y,
                     const float* __restrict__ w, const float* __restrict__ b,
                     float* __restrict__ out) {
  const int row = blockIdx.x * 4 + (threadIdx.x >> 6);
  const int lane = threadIdx.x & 63;
  const bf16* x = X + (size_t)row * 768;
  const float* y = Y + (size_t)row * 768;
  float v[12];
  float s = 0.0f;
#pragma unroll
  for (int i = 0; i < 3; i++) {
    const int c = lane * 4 + i * 256;
    const float4 yf = *(const float4*)(y + c);
    v[i * 4 + 0] = (float)x[c + 0] + yf.x; v[i * 4 + 1] = (float)x[c + 1] + yf.y;
    v[i * 4 + 2] = (float)x[c + 2] + yf.z; v[i * 4 + 3] = (float)x[c + 3] + yf.w;
    s += v[i * 4] + v[i * 4 + 1] + v[i * 4 + 2] + v[i * 4 + 3];
  }
#pragma unroll
  for (int off = 32; off > 0; off >>= 1) s += __shfl_xor(s, off, 64);
  const float mu = s * (1.0f / 768.0f);
  float var = 0.0f;
#pragma unroll
  for (int i = 0; i < 12; i++) { const float d = v[i] - mu; var += d * d; }
#pragma unroll
  for (int off = 32; off > 0; off >>= 1) var += __shfl_xor(var, off, 64);
  const float rs = rsqrtf(var * (1.0f / 768.0f) + 1e-5f);
#pragma unroll
  for (int i = 0; i < 12; i++) {
    const int c = lane * 4 + (i >> 2) * 256 + (i & 3);
    out[(size_t)row * 768 + c] = (v[i] - mu) * rs * w[c] + b[c];
  }
}

// ---------------------------------------------------------------------------
extern "C" void kernel_launch(void* const* d_in, const int* in_sizes, int n_in,
                              void* d_out, int out_size, void* d_ws, size_t ws_size,
                              hipStream_t stream) {
  (void)in_sizes; (void)n_in; (void)out_size; (void)ws_size;
  const float* src   = (const float*)d_in[0];
  const float* w_qkv = (const float*)d_in[1];
  const float* b_qkv = (const float*)d_in[2];
  const float* w_out = (const float*)d_in[3];
  const float* b_out = (const float*)d_in[4];
  const float* w1    = (const float*)d_in[5];
  const float* b1    = (const float*)d_in[6];
  const float* w2    = (const float*)d_in[7];
  const float* b2    = (const float*)d_in[8];
  const float* ln1w  = (const float*)d_in[9];
  const float* ln1b  = (const float*)d_in[10];
  const float* ln2w  = (const float*)d_in[11];
  const float* ln2b  = (const float*)d_in[12];
  float* out = (float*)d_out;

  // ws layout (peak 64,487,424 B — validated)
  char* ws = (char*)d_ws;
  bf16* wqkvb = (bf16*)ws;                     // 2304*768 (dead after g1)
  bf16* woutb = (bf16*)(ws + 3538944);         //  768*768
  bf16* w1b   = (bf16*)(ws + 4718592);         // 3072*768
  bf16* w2b   = (bf16*)(ws + 9437184);         //  768*3072
  bf16* srcb  = (bf16*)(ws + 14155776);
  bf16* QK    = (bf16*)(ws + 26738688);
  bf16* Vt    = (bf16*)(ws + 51904512);
  // attn K-split partials:
  bf16* Opart = (bf16*)d_out;                  // [2][8192][768] bf16 = 25.2 MB
  float* lbuf = (float*)ws;                    // [2][8192][12] f32 (wqkvb dead)
  bf16* ctx   = (bf16*)(ws + 14155776);        // srcb region (dead after g1)
  float* attn_out = (float*)(ws + 26738688);   // QK region (dead after attn)
  bf16* x1b   = (bf16*)(ws + 51904512);        // Vt region (dead after attn)
  bf16* hbuf  = (bf16*)(ws + 14155776);        // ctx+QK regions (25.2 MB; both
                                               // dead after LN1)
  float* ffn  = out;                           // d_out (Opart dead after combine)

  // 0) all casts in one dispatch
  cast_all_kernel<<<13056, 256, 0, stream>>>(
      w_qkv, wqkvb, w_out, woutb, w1, w1b, w2, w2b, src, srcb);

  // 1) fused QKV projection: bn<12 -> QK [8192,1536]; bn>=12 -> Vt scatter
  gemm_bt_kernel<0, 2, 0, 128, bf16><<<dim3(64, 18), 256, 0, stream>>>(
      srcb, wqkvb, b_qkv, QK, 1536, 768, 768, 768, Vt);
  // 3) partial attn over 2 key-splits (256 q per block), XCD-group swizzled
  attn_kernel<<<dim3(32, 12, 2), 256, 0, stream>>>(QK, Vt, Opart, lbuf);
  // 3.5) ctx = (O0+O1)/(l0+l1)  (bf16, into srcb region)
  attn_combine_kernel<<<3072, 256, 0, stream>>>(Opart, lbuf, ctx);
  // 4) attn_out = ctx @ w_out^T + b_out (f32), narrow 64-col tile -> 3 blk/CU
  gemm_bt_kernel<0, 0, 0, 64, float><<<dim3(64, 12), 256, 0, stream>>>(
      ctx, woutb, b_out, attn_out, 768, 768, 768, 768, nullptr);
  // 5) x1b = LN(src + attn_out)  (bf16)
  add_ln_b_kernel<<<2048, 256, 0, stream>>>(src, attn_out, ln1w, ln1b, x1b);
  // 6/7) FFN, 2 chunks of 1536 h-columns; FFN2 narrow 64-col tile (3 blk/CU);
  // ffn accumulates f32 in d_out (c1 fused read-add-write).
  for (int c = 0; c < 2; c++) {
    gemm_bt_kernel<1, 0, 0, 128, bf16><<<dim3(64, 12), 256, 0, stream>>>(
        x1b, w1b + (size_t)c * 1536 * 768, b1 + c * 1536, hbuf, 1536, 768, 768,
        768, nullptr);
    if (c == 0)
      gemm_bt_kernel<0, 0, 0, 64, float><<<dim3(64, 12), 256, 0, stream>>>(
          hbuf, w2b + c * 1536, b2, ffn, 768, 1536, 1536, 3072, nullptr);
    else
      gemm_bt_kernel<0, 0, 1, 64, float><<<dim3(64, 12), 256, 0, stream>>>(
          hbuf, w2b + c * 1536, b2, ffn, 768, 1536, 1536, 3072, nullptr);
  }
  // 8) out = LN(x1b + ffn)  (in-place over ffn in d_out; per-thread RAW only)
  add_ln_f_kernel<<<2048, 256, 0, stream>>>(x1b, ffn, ln2w, ln2b, out);
}

// Round 12
// 445.019 us; speedup vs baseline: 1.1269x; 1.1269x over previous
//
#include <hip/hip_runtime.h>
#include <hip/hip_bf16.h>

typedef __hip_bfloat16 bf16;
typedef __attribute__((ext_vector_type(8))) short s16x8;   // 8 bf16 = 4 VGPRs
typedef __attribute__((ext_vector_type(4))) float f32x4;

#define MFMA16x16x32(A, B, C) __builtin_amdgcn_mfma_f32_16x16x32_bf16((A), (B), (C), 0, 0, 0)

__device__ __forceinline__ void async_copy16(const bf16* g, bf16* l) {
  __builtin_amdgcn_global_load_lds(
      (const __attribute__((address_space(1))) void*)g,
      (__attribute__((address_space(3))) void*)l, 16, 0, 0);
}

// XOR-swizzled LDS addressing for 128-B rows (64 bf16), 16-B chunks:
// chunk' = chunk ^ (row&7). The ONLY empirically-validated conflict-free
// pattern on this HW (R8 low-conflict vs R9/R11 narrow-row blowups).
__device__ __forceinline__ int SW(int row, int chunk) {
  return row * 64 + (((chunk) ^ (row & 7)) << 3);
}

// ---------------------------------------------------------------------------
// merged cast: all 5 f32->bf16 casts in ONE dispatch (block-range routing).
// blocks: w_qkv 1728 | w_out 576 | w1 2304 | w2 2304 | src 6144  = 13056
// ---------------------------------------------------------------------------
__global__ __launch_bounds__(256)
void cast_all_kernel(const float* __restrict__ s0, bf16* __restrict__ d0,
                     const float* __restrict__ s1, bf16* __restrict__ d1,
                     const float* __restrict__ s2, bf16* __restrict__ d2,
                     const float* __restrict__ s3, bf16* __restrict__ d3,
                     const float* __restrict__ s4, bf16* __restrict__ d4) {
  int blk = blockIdx.x;
  const float* in; bf16* out;
  if (blk < 1728)      { in = s0; out = d0; }
  else if (blk < 2304) { in = s1; out = d1; blk -= 1728; }
  else if (blk < 4608) { in = s2; out = d2; blk -= 2304; }
  else if (blk < 6912) { in = s3; out = d3; blk -= 4608; }
  else                 { in = s4; out = d4; blk -= 6912; }
  const int i = (blk * 256 + threadIdx.x) * 4;
  const float4 f = *(const float4*)(in + i);
  out[i + 0] = (bf16)f.x; out[i + 1] = (bf16)f.y;
  out[i + 2] = (bf16)f.z; out[i + 3] = (bf16)f.w;
}

// ---------------------------------------------------------------------------
// GEMM: C = A[M,K]b @ B[N,K]^T b (+bias f32) (+ReLU) (+fp32 accumulate).
// 128xCN tile (CN = 128 or 64), BK=32, 256 threads, double-buffered LDS,
// one barrier per K-step. CN=64 narrow tile -> 3 blocks/CU for N=768.
// VT=0: plain store. VT=2: fused QKV routing (cols <1536 -> C, >=1536 ->
// per-head Vt scatter into C2); CN must be 128 for VT=2.
// ---------------------------------------------------------------------------
template <int RELU, int VT, int ACCUM, int CN, typename OutT>
__global__ __launch_bounds__(256)
void gemm_bt_kernel(const bf16* __restrict__ A, const bf16* __restrict__ B,
                    const float* __restrict__ bias, OutT* __restrict__ C,
                    int N, int K, int lda, int ldb, bf16* __restrict__ C2) {
  constexpr int NJ = CN / 32;              // col 16x16 tiles per wave (4 or 2)
  __shared__ __align__(16) bf16 As[2][128 * 32];
  __shared__ __align__(16) bf16 Bs[2][CN * 32];

  const int t = threadIdx.x;
  const int lane = t & 63;
  const int wave = t >> 6;
  const int wm = (wave >> 1) << 6;
  const int wn = (wave & 1) * (CN / 2);
  const int col16 = lane & 15;
  const int quad = lane >> 4;
  const int bm = blockIdx.x;
  const int bn = blockIdx.y;

  const bf16* Ag = A + (size_t)(bm * 128 + (t >> 2)) * lda + (t & 3) * 8;
  const bf16* Bg = B + (size_t)(bn * CN + (t >> 2)) * ldb + (t & 3) * 8;

  f32x4 acc[4][NJ] = {};

  // prologue: stage K-tile 0 into buffer 0
  async_copy16(Ag, &As[0][0] + t * 8);
  async_copy16(Ag + (size_t)64 * lda, &As[0][0] + 2048 + t * 8);
  async_copy16(Bg, &Bs[0][0] + t * 8);
  if (CN == 128)
    async_copy16(Bg + (size_t)64 * ldb, &Bs[0][0] + 2048 + t * 8);

  int n = 0;
  for (int k0 = 0; k0 < K; k0 += 32, n ^= 1) {
    __syncthreads();   // compiler drains vmcnt here -> buf n resident
    if (k0 + 32 < K) {
      const int k1 = k0 + 32;
      async_copy16(Ag + k1, &As[n ^ 1][0] + t * 8);
      async_copy16(Ag + (size_t)64 * lda + k1, &As[n ^ 1][0] + 2048 + t * 8);
      async_copy16(Bg + k1, &Bs[n ^ 1][0] + t * 8);
      if (CN == 128)
        async_copy16(Bg + (size_t)64 * ldb + k1, &Bs[n ^ 1][0] + 2048 + t * 8);
    }
    const bf16* asn = &As[n][0];
    const bf16* bsn = &Bs[n][0];

    s16x8 af[4], bfr[NJ];
#pragma unroll
    for (int i = 0; i < 4; i++)
      af[i] = *(const s16x8*)(asn + (wm + i * 16 + col16) * 32 + quad * 8);
#pragma unroll
    for (int j = 0; j < NJ; j++)
      bfr[j] = *(const s16x8*)(bsn + (wn + j * 16 + col16) * 32 + quad * 8);
#pragma unroll
    for (int i = 0; i < 4; i++)
#pragma unroll
      for (int j = 0; j < NJ; j++)
        acc[i][j] = MFMA16x16x32(af[i], bfr[j], acc[i][j]);
  }

  const int row0 = bm * 128 + wm + quad * 4;
  const int col0 = bn * CN + wn + col16;
#pragma unroll
  for (int j = 0; j < NJ; j++) {
    const int col = col0 + j * 16;
    const float bv = ACCUM ? 0.0f : bias[col];
#pragma unroll
    for (int i = 0; i < 4; i++) {
#pragma unroll
      for (int r = 0; r < 4; r++) {
        float v = acc[i][j][r] + bv;
        if (RELU) v = fmaxf(v, 0.0f);
        const int row = row0 + i * 16 + r;
        if (VT == 2) {
          if (col < 1536) {
            C[(size_t)row * N + col] = (OutT)v;
          } else {
            const int cc = col - 1536;
            C2[(size_t)((row >> 12) * 12 + (cc >> 6)) * 262144 +
               (cc & 63) * 4096 + (row & 4095)] = (bf16)v;
          }
        } else {
          const size_t idx = (size_t)row * N + col;
          if (ACCUM) v += ((const float*)C)[idx];
          C[idx] = (OutT)v;
        }
      }
    }
  }
}

// ---------------------------------------------------------------------------
// Flash attention, round-12: 32 KB LDS (3 blocks/CU CONFIRMED in R11) with
// ALL tiles in the proven 128-B-row SW() layout via row-packing:
//   Ks [32 k][64 d]            (4 KB, dbuf)  -- rows = keys, as R11 (clean)
//   Vs packed: row r = {d=2r | d=2r+1} x 32 keys  (4 KB, dbuf)
//   Ps packed: row r = {q=2r | q=2r+1} x 32 keys  (4 KB/wave x 4)
// KVBLK=32, one barrier per tile. Same math as R8/R10: S^T formulation,
// shift-free exp2 softmax (|s_log2|<=~8), ones-MFMA l on the matrix pipe,
// 64 q/wave, K-SPLIT=2, XCD-group swizzle (FETCH 104->18.5 MB).
// ---------------------------------------------------------------------------
__global__ __launch_bounds__(256, 3)
void attn_kernel(const bf16* __restrict__ QK, const bf16* __restrict__ Vt,
                 bf16* __restrict__ Opart, float* __restrict__ lbuf) {
  // pool (bf16): Ks[2] @0 (2048 ea) | Vs[2] @4096 | Ps[4] @8192 (2048 ea)
  __shared__ __align__(16) bf16 pool[16384];   // 32768 B

  const int t = threadIdx.x, lane = t & 63, wave = t >> 6;
  const int col16 = lane & 15, quad = lane >> 4;

  // XCD-group swizzle: w -> (work-x, head h, batch b); g%8 pins the KV
  // panel group to one XCD's L2.
  const int w = blockIdx.x + 32 * (blockIdx.y + 12 * blockIdx.z);
  const int g = (w & 7) + 8 * ((w >> 3) >> 5);
  const int x = (w >> 3) & 31;
  const int b = g / 12, h = g % 12;
  const int ks = x >> 4;                          // key-split index (0/1)
  const int qblk = x & 15;
  const int qw0 = qblk * 256 + wave * 64;

  // Q as B-frags (4 qtiles), pre-scaled by 0.125*log2(e)
  s16x8 bq[4][2];
#pragma unroll
  for (int qt = 0; qt < 4; qt++)
#pragma unroll
    for (int s = 0; s < 2; s++) {
      union { s16x8 v; bf16 hh[8]; } u;
      u.v = *(const s16x8*)(QK + (size_t)(b * 4096 + qw0 + qt * 16 + col16) * 1536 +
                            h * 64 + s * 32 + quad * 8);
#pragma unroll
      for (int e = 0; e < 8; e++) u.hh[e] = (bf16)((float)u.hh[e] * 0.18033688f);
      bq[qt][s] = u.v;
    }

  // all-ones A-fragment for the l-accumulating MFMA
  union { s16x8 v; short s_[8]; } uo1;
#pragma unroll
  for (int e = 0; e < 8; e++) uo1.s_[e] = (short)0x3F80;  // bf16 1.0
  const s16x8 aones = uo1.v;

  // staging (pre-swizzled global source, linear LDS dest t*8):
  // K tile [32 k][64 d]: t -> row=t>>3, content chunk cc=(t&7)^(row&7),
  //   src = key (k0+row), d-chunk cc.
  // V packed tile: t -> row=t>>3, cc=(t&7)^(row&7); d = 2*row + (cc>>2),
  //   key-chunk = cc&3 (8 keys each).
  const int srow = t >> 3;
  const int scc = (t & 7) ^ (srow & 7);
  const bf16* kgb = QK + (size_t)(b * 4096) * 1536 + 768 + h * 64;
  const bf16* vgb = Vt + (size_t)(b * 12 + h) * 262144;
  const bf16* ksrc = kgb + (size_t)srow * 1536 + scc * 8;               // + k*1536
  const bf16* vsrc = vgb + (size_t)(2 * srow + (scc >> 2)) * 4096 +
                     (scc & 3) * 8;                                     // + k0

  f32x4 o[4][4] = {};            // O^T [dtile][qtile]
  f32x4 lacc[4] = {};            // l per qtile (all C-rows identical)
  bf16* pw = pool + 8192 + wave * 2048;   // packed P^T: 32 rows x 64 elem

  const int kbeg = ks * 2048, kend = kbeg + 2048;

  // prologue: stage first 32-key tile into buffer 0
  async_copy16(ksrc + (size_t)kbeg * 1536, pool + t * 8);
  async_copy16(vsrc + kbeg, pool + 4096 + t * 8);

  int n = 0;
  for (int k0 = kbeg; k0 < kend; k0 += 32, n ^= 1) {
    // barrier drains vmcnt -> tile k0 resident in buf n for all waves
    __syncthreads();
    if (k0 + 32 < kend) {
      async_copy16(ksrc + (size_t)(k0 + 32) * 1536, pool + (n ^ 1) * 2048 + t * 8);
      async_copy16(vsrc + (k0 + 32), pool + 4096 + (n ^ 1) * 2048 + t * 8);
    }
    const bf16* ksn = pool + n * 2048;          // [32 k][64 d] SW
    const bf16* vsn = pool + 4096 + n * 2048;   // packed V SW

    // K^T fragments (2 keytiles x 2 d-slices), read ONCE, used by 4 qtiles
    s16x8 ak[2][2];
#pragma unroll
    for (int s = 0; s < 2; s++)
#pragma unroll
      for (int kt = 0; kt < 2; kt++)
        ak[s][kt] = *(const s16x8*)(ksn + SW(kt * 16 + col16, s * 4 + quad));

    // per-keytile: S^T (log2 domain) -> shift-free softmax -> packed P^T
#pragma unroll
    for (int kt = 0; kt < 2; kt++) {
      f32x4 st[4] = {};
#pragma unroll
      for (int s = 0; s < 2; s++)
#pragma unroll
        for (int qt = 0; qt < 4; qt++)
          st[qt] = MFMA16x16x32(ak[s][kt], bq[qt][s], st[qt]);
#pragma unroll
      for (int qt = 0; qt < 4; qt++) {
        union { unsigned long long u; bf16 hh[4]; } pk;
#pragma unroll
        for (int r = 0; r < 4; r++)
          pk.hh[r] = (bf16)__builtin_amdgcn_exp2f(st[qt][r]);
        // q = qt*16+col16; row = q>>1; 8B-slot = (q&1)*8 + kt*4 + quad;
        // chunk = slot>>1 XOR (row&7); sub8 = slot&1.
        const int q = qt * 16 + col16;
        const int row = q >> 1;
        const int chunk = ((q & 1) * 4 + kt * 2 + (quad >> 1)) ^ (row & 7);
        *(unsigned long long*)(pw + row * 64 + (chunk << 3) + (quad & 1) * 4) =
            pk.u;
      }
    }
    asm volatile("s_waitcnt lgkmcnt(0)" ::: "memory");

    // l += ones @ P^T (matrix pipe);  O^T += V^T @ P^T  (one K=32 slice)
    s16x8 bp[4];
#pragma unroll
    for (int qt = 0; qt < 4; qt++) {
      const int q = qt * 16 + col16;
      bp[qt] = *(const s16x8*)(pw + SW(q >> 1, (q & 1) * 4 + quad));
    }
#pragma unroll
    for (int qt = 0; qt < 4; qt++)
      lacc[qt] = MFMA16x16x32(aones, bp[qt], lacc[qt]);
#pragma unroll
    for (int dt = 0; dt < 4; dt++) {
      const int d = dt * 16 + col16;
      const s16x8 av = *(const s16x8*)(vsn + SW(d >> 1, (d & 1) * 4 + quad));
#pragma unroll
      for (int qt = 0; qt < 4; qt++)
        o[dt][qt] = MFMA16x16x32(av, bp[qt], o[dt][qt]);
    }
  }

  // partial l: C/D col = lane&15 = q; every C-row holds the same value.
  if (lane < 16) {
#pragma unroll
    for (int qt = 0; qt < 4; qt++)
      lbuf[(size_t)ks * 98304 + (size_t)(b * 4096 + qw0 + qt * 16 + lane) * 12 + h] =
          lacc[qt][0];
  }

  // epilogue: repurpose the whole pool as per-wave [64 q][64 d] transpose
  // buffers (4 x 8 KB); barrier first — K/V/P regions are dead. (R9-proven.)
  __syncthreads();
  bf16* ep = pool + wave * 4096;
#pragma unroll
  for (int qt = 0; qt < 4; qt++)
#pragma unroll
    for (int dt = 0; dt < 4; dt++)
#pragma unroll
      for (int r = 0; r < 4; r++)
        ep[(qt * 16 + col16) * 64 + (((dt * 2 + (quad >> 1)) ^ (col16 & 7)) << 3) +
           (quad & 1) * 4 + r] = (bf16)(o[dt][qt][r]);
  asm volatile("s_waitcnt lgkmcnt(0)" ::: "memory");
  const int qrow = lane >> 1, chalf = (lane & 1) * 4;
#pragma unroll
  for (int h2 = 0; h2 < 2; h2++) {
    const int rl = h2 * 32 + qrow;
    bf16* dst = Opart + (size_t)ks * 6291456 +
                (size_t)(b * 4096 + qw0 + rl) * 768 + h * 64 + chalf * 8;
#pragma unroll
    for (int i = 0; i < 4; i++)
      *(s16x8*)(dst + i * 8) = *(const s16x8*)(ep + SW(rl, chalf + i));
  }
}

// ---------------------------------------------------------------------------
// combine: ctx = (O0 + O1) / (l0 + l1); 8 cols per thread, fully coalesced.
// ---------------------------------------------------------------------------
__global__ __launch_bounds__(256)
void attn_combine_kernel(const bf16* __restrict__ Opart,
                         const float* __restrict__ lbuf,
                         bf16* __restrict__ ctx) {
  const int i = blockIdx.x * 256 + threadIdx.x;   // [0, 8192*96)
  const int row = i / 96, c8 = i % 96;
  const int h = c8 >> 3;
  const float inv = 1.0f / (lbuf[(size_t)row * 12 + h] +
                            lbuf[98304 + (size_t)row * 12 + h]);
  union { s16x8 v; bf16 hh[8]; } ua, ub, uo;
  ua.v = *(const s16x8*)(Opart + (size_t)row * 768 + c8 * 8);
  ub.v = *(const s16x8*)(Opart + 6291456 + (size_t)row * 768 + c8 * 8);
#pragma unroll
  for (int j = 0; j < 8; j++)
    uo.hh[j] = (bf16)(((float)ua.hh[j] + (float)ub.hh[j]) * inv);
  *(s16x8*)(ctx + (size_t)row * 768 + c8 * 8) = uo.v;
}

// ---------------------------------------------------------------------------
// LN variants: ln_b: bf16 out of LN(f32 + f32); ln_f: f32 out of LN(bf16+f32)
// ---------------------------------------------------------------------------
__global__ __launch_bounds__(256)
void add_ln_b_kernel(const float* __restrict__ X, const float* __restrict__ Y,
                     const float* __restrict__ w, const float* __restrict__ b,
                     bf16* __restrict__ out) {
  const int row = blockIdx.x * 4 + (threadIdx.x >> 6);
  const int lane = threadIdx.x & 63;
  const float* x = X + (size_t)row * 768;
  const float* y = Y + (size_t)row * 768;
  float v[12];
  float s = 0.0f;
#pragma unroll
  for (int i = 0; i < 3; i++) {
    const int c = lane * 4 + i * 256;
    const float4 xf = *(const float4*)(x + c);
    const float4 yf = *(const float4*)(y + c);
    v[i * 4 + 0] = xf.x + yf.x; v[i * 4 + 1] = xf.y + yf.y;
    v[i * 4 + 2] = xf.z + yf.z; v[i * 4 + 3] = xf.w + yf.w;
    s += v[i * 4] + v[i * 4 + 1] + v[i * 4 + 2] + v[i * 4 + 3];
  }
#pragma unroll
  for (int off = 32; off > 0; off >>= 1) s += __shfl_xor(s, off, 64);
  const float mu = s * (1.0f / 768.0f);
  float var = 0.0f;
#pragma unroll
  for (int i = 0; i < 12; i++) { const float d = v[i] - mu; var += d * d; }
#pragma unroll
  for (int off = 32; off > 0; off >>= 1) var += __shfl_xor(var, off, 64);
  const float rs = rsqrtf(var * (1.0f / 768.0f) + 1e-5f);
#pragma unroll
  for (int i = 0; i < 12; i++) {
    const int c = lane * 4 + (i >> 2) * 256 + (i & 3);
    out[(size_t)row * 768 + c] = (bf16)((v[i] - mu) * rs * w[c] + b[c]);
  }
}

__global__ __launch_bounds__(256)
void add_ln_f_kernel(const bf16* __restrict__ X, const float* __restrict__ Y,
                     const float* __restrict__ w, const float* __restrict__ b,
                     float* __restrict__ out) {
  const int row = blockIdx.x * 4 + (threadIdx.x >> 6);
  const int lane = threadIdx.x & 63;
  const bf16* x = X + (size_t)row * 768;
  const float* y = Y + (size_t)row * 768;
  float v[12];
  float s = 0.0f;
#pragma unroll
  for (int i = 0; i < 3; i++) {
    const int c = lane * 4 + i * 256;
    const float4 yf = *(const float4*)(y + c);
    v[i * 4 + 0] = (float)x[c + 0] + yf.x; v[i * 4 + 1] = (float)x[c + 1] + yf.y;
    v[i * 4 + 2] = (float)x[c + 2] + yf.z; v[i * 4 + 3] = (float)x[c + 3] + yf.w;
    s += v[i * 4] + v[i * 4 + 1] + v[i * 4 + 2] + v[i * 4 + 3];
  }
#pragma unroll
  for (int off = 32; off > 0; off >>= 1) s += __shfl_xor(s, off, 64);
  const float mu = s * (1.0f / 768.0f);
  float var = 0.0f;
#pragma unroll
  for (int i = 0; i < 12; i++) { const float d = v[i] - mu; var += d * d; }
#pragma unroll
  for (int off = 32; off > 0; off >>= 1) var += __shfl_xor(var, off, 64);
  const float rs = rsqrtf(var * (1.0f / 768.0f) + 1e-5f);
#pragma unroll
  for (int i = 0; i < 12; i++) {
    const int c = lane * 4 + (i >> 2) * 256 + (i & 3);
    out[(size_t)row * 768 + c] = (v[i] - mu) * rs * w[c] + b[c];
  }
}

// ---------------------------------------------------------------------------
extern "C" void kernel_launch(void* const* d_in, const int* in_sizes, int n_in,
                              void* d_out, int out_size, void* d_ws, size_t ws_size,
                              hipStream_t stream) {
  (void)in_sizes; (void)n_in; (void)out_size; (void)ws_size;
  const float* src   = (const float*)d_in[0];
  const float* w_qkv = (const float*)d_in[1];
  const float* b_qkv = (const float*)d_in[2];
  const float* w_out = (const float*)d_in[3];
  const float* b_out = (const float*)d_in[4];
  const float* w1    = (const float*)d_in[5];
  const float* b1    = (const float*)d_in[6];
  const float* w2    = (const float*)d_in[7];
  const float* b2    = (const float*)d_in[8];
  const float* ln1w  = (const float*)d_in[9];
  const float* ln1b  = (const float*)d_in[10];
  const float* ln2w  = (const float*)d_in[11];
  const float* ln2b  = (const float*)d_in[12];
  float* out = (float*)d_out;

  // ws layout (peak 64,487,424 B — validated)
  char* ws = (char*)d_ws;
  bf16* wqkvb = (bf16*)ws;                     // 2304*768 (dead after g1)
  bf16* woutb = (bf16*)(ws + 3538944);         //  768*768
  bf16* w1b   = (bf16*)(ws + 4718592);         // 3072*768
  bf16* w2b   = (bf16*)(ws + 9437184);         //  768*3072
  bf16* srcb  = (bf16*)(ws + 14155776);
  bf16* QK    = (bf16*)(ws + 26738688);
  bf16* Vt    = (bf16*)(ws + 51904512);
  // attn K-split partials:
  bf16* Opart = (bf16*)d_out;                  // [2][8192][768] bf16 = 25.2 MB
  float* lbuf = (float*)ws;                    // [2][8192][12] f32 (wqkvb dead)
  bf16* ctx   = (bf16*)(ws + 14155776);        // srcb region (dead after g1)
  float* attn_out = (float*)(ws + 26738688);   // QK region (dead after attn)
  bf16* x1b   = (bf16*)(ws + 51904512);        // Vt region (dead after attn)
  bf16* hbuf  = (bf16*)(ws + 14155776);        // ctx+QK regions (25.2 MB; both
                                               // dead after LN1)
  float* ffn  = out;                           // d_out (Opart dead after combine)

  // 0) all casts in one dispatch
  cast_all_kernel<<<13056, 256, 0, stream>>>(
      w_qkv, wqkvb, w_out, woutb, w1, w1b, w2, w2b, src, srcb);

  // 1) fused QKV projection: bn<12 -> QK [8192,1536]; bn>=12 -> Vt scatter
  gemm_bt_kernel<0, 2, 0, 128, bf16><<<dim3(64, 18), 256, 0, stream>>>(
      srcb, wqkvb, b_qkv, QK, 1536, 768, 768, 768, Vt);
  // 3) partial attn over 2 key-splits (256 q per block), XCD-group swizzled
  attn_kernel<<<dim3(32, 12, 2), 256, 0, stream>>>(QK, Vt, Opart, lbuf);
  // 3.5) ctx = (O0+O1)/(l0+l1)  (bf16, into srcb region)
  attn_combine_kernel<<<3072, 256, 0, stream>>>(Opart, lbuf, ctx);
  // 4) attn_out = ctx @ w_out^T + b_out (f32), narrow 64-col tile -> 3 blk/CU
  gemm_bt_kernel<0, 0, 0, 64, float><<<dim3(64, 12), 256, 0, stream>>>(
      ctx, woutb, b_out, attn_out, 768, 768, 768, 768, nullptr);
  // 5) x1b = LN(src + attn_out)  (bf16)
  add_ln_b_kernel<<<2048, 256, 0, stream>>>(src, attn_out, ln1w, ln1b, x1b);
  // 6/7) FFN, 2 chunks of 1536 h-columns; FFN2 narrow 64-col tile (3 blk/CU);
  // ffn accumulates f32 in d_out (c1 fused read-add-write).
  for (int c = 0; c < 2; c++) {
    gemm_bt_kernel<1, 0, 0, 128, bf16><<<dim3(64, 12), 256, 0, stream>>>(
        x1b, w1b + (size_t)c * 1536 * 768, b1 + c * 1536, hbuf, 1536, 768, 768,
        768, nullptr);
    if (c == 0)
      gemm_bt_kernel<0, 0, 0, 64, float><<<dim3(64, 12), 256, 0, stream>>>(
          hbuf, w2b + c * 1536, b2, ffn, 768, 1536, 1536, 3072, nullptr);
    else
      gemm_bt_kernel<0, 0, 1, 64, float><<<dim3(64, 12), 256, 0, stream>>>(
          hbuf, w2b + c * 1536, b2, ffn, 768, 1536, 1536, 3072, nullptr);
  }
  // 8) out = LN(x1b + ffn)  (in-place over ffn in d_out; per-thread RAW only)
  add_ln_f_kernel<<<2048, 256, 0, stream>>>(x1b, ffn, ln2w, ln2b, out);
}